// Round 11
// baseline (204.631 us; speedup 1.0000x reference)
//
#include <hip/hip_runtime.h>
#include <hip/hip_fp16.h>

#define N_NODES 50000
#define N_EDGES 800000
#define N_FEAT 128
#define HIDDEN 64
#define N_CLASSES 16
#define NBLK_NODE 196   // number of 256-node dst tiles (ceil(50000/256))
#define TCAP 8192       // per-tile bucket capacity (recs); mean 4083, sigma ~64

// tileCur[t] = t*TCAP (bucket base cursors)
__global__ void k_init(int* __restrict__ tileCur) {
    int tid = threadIdx.x;
    if (tid < NBLK_NODE) tileCur[tid] = tid * TCAP;
}

// Partition edges into 196 fixed-capacity dst-tile buckets. Per block: LDS
// histogram, ONE global atomic per (block,tile) reserves a contiguous sub-run
// -> block-owned 4B record stores merge in L2. record: src | dstLocal<<16
__global__ __launch_bounds__(256) void k_part(const int* __restrict__ ei,
                                              int* __restrict__ tileCur,
                                              int* __restrict__ binned) {
    __shared__ int cnt[NBLK_NODE], base[NBLK_NODE], cur[NBLK_NODE];
    int tid = threadIdx.x;
    int start = blockIdx.x * 4096;
    if (tid < NBLK_NODE) cnt[tid] = 0;
    __syncthreads();
    int s[16], d[16];
#pragma unroll
    for (int u = 0; u < 4; ++u) {
        int e0 = start + u * 1024 + tid * 4;
        if (e0 + 4 <= N_EDGES) {
            int4 s4 = *(const int4*)&ei[e0];
            int4 d4 = *(const int4*)&ei[N_EDGES + e0];
            s[u * 4 + 0] = s4.x; s[u * 4 + 1] = s4.y; s[u * 4 + 2] = s4.z; s[u * 4 + 3] = s4.w;
            d[u * 4 + 0] = d4.x; d[u * 4 + 1] = d4.y; d[u * 4 + 2] = d4.z; d[u * 4 + 3] = d4.w;
#pragma unroll
            for (int q = 0; q < 4; ++q) atomicAdd(&cnt[d[u * 4 + q] >> 8], 1);
        } else {
#pragma unroll
            for (int q = 0; q < 4; ++q) {
                int e = e0 + q;
                if (e < N_EDGES) {
                    s[u * 4 + q] = ei[e];
                    d[u * 4 + q] = ei[N_EDGES + e];
                    atomicAdd(&cnt[d[u * 4 + q] >> 8], 1);
                } else s[u * 4 + q] = -1;
            }
        }
    }
    __syncthreads();
    if (tid < NBLK_NODE) {
        base[tid] = atomicAdd(&tileCur[tid], cnt[tid]);
        cur[tid] = 0;
    }
    __syncthreads();
#pragma unroll
    for (int u = 0; u < 16; ++u) {
        if (s[u] < 0) continue;
        int t = d[u] >> 8;
        int r = atomicAdd(&cur[t], 1);
        int p = base[t] + r;
        if (p < (t + 1) * TCAP)  // bucket-bound guard (never hit for uniform input)
            binned[p] = s[u] | ((d[u] & 255) << 16);
    }
}

// Per-tile counting sort (bucketed layout). Also derives degree -> dinv and
// per-node {start,count} rse. Fully LDS-staged; coalesced int4 csr writes.
__global__ __launch_bounds__(256) void k_finesort(const int* __restrict__ binned,
                                                  const int* __restrict__ tileCur,
                                                  int* __restrict__ csr,
                                                  int2* __restrict__ rse,
                                                  float* __restrict__ dinv) {
    __shared__ int stage[TCAP];
    __shared__ int sc[256];
    __shared__ int cnt256[256];
    __shared__ int nodeOff[256];
    int tid = threadIdx.x;
    int tb = blockIdx.x;
    int beg = tb * TCAP;
    int m = tileCur[tb] - beg;
    if (m > TCAP) m = TCAP;
    cnt256[tid] = 0;
    __syncthreads();
    const int4* b4 = (const int4*)(binned + beg);
    int nv = m >> 2;
    for (int i = tid; i < nv; i += 256) {
        int4 r = b4[i];
        atomicAdd(&cnt256[(r.x >> 16) & 255], 1);
        atomicAdd(&cnt256[(r.y >> 16) & 255], 1);
        atomicAdd(&cnt256[(r.z >> 16) & 255], 1);
        atomicAdd(&cnt256[(r.w >> 16) & 255], 1);
    }
    for (int i = (m & ~3) + tid; i < m; i += 256)
        atomicAdd(&cnt256[(binned[beg + i] >> 16) & 255], 1);
    __syncthreads();
    int myc = cnt256[tid];
    sc[tid] = myc;
    __syncthreads();
#pragma unroll
    for (int off = 1; off < 256; off <<= 1) {
        int t = (tid >= off) ? sc[tid - off] : 0;
        __syncthreads();
        sc[tid] += t;
        __syncthreads();
    }
    int off0 = sc[tid] - myc;
    nodeOff[tid] = off0;
    int gnode = tb * 256 + tid;
    if (gnode < N_NODES) {
        dinv[gnode] = rsqrtf((float)myc + 1.0f);  // deg = in-edges + self-loop
        rse[gnode] = make_int2(beg + off0, myc);
    }
    cnt256[tid] = 0;
    __syncthreads();
    for (int i = tid; i < nv; i += 256) {
        int4 r = b4[i];
        int rr;
        rr = atomicAdd(&cnt256[(r.x >> 16) & 255], 1); stage[nodeOff[(r.x >> 16) & 255] + rr] = r.x & 0xFFFF;
        rr = atomicAdd(&cnt256[(r.y >> 16) & 255], 1); stage[nodeOff[(r.y >> 16) & 255] + rr] = r.y & 0xFFFF;
        rr = atomicAdd(&cnt256[(r.z >> 16) & 255], 1); stage[nodeOff[(r.z >> 16) & 255] + rr] = r.z & 0xFFFF;
        rr = atomicAdd(&cnt256[(r.w >> 16) & 255], 1); stage[nodeOff[(r.w >> 16) & 255] + rr] = r.w & 0xFFFF;
    }
    for (int i = (m & ~3) + tid; i < m; i += 256) {
        int rec = binned[beg + i];
        int dl = (rec >> 16) & 255;
        int rr = atomicAdd(&cnt256[dl], 1);
        stage[nodeOff[dl] + rr] = rec & 0xFFFF;
    }
    __syncthreads();
    int4* c4 = (int4*)(csr + beg);
    for (int i = tid; i < nv; i += 256) c4[i] = ((const int4*)stage)[i];
    for (int i = (m & ~3) + tid; i < m; i += 256) csr[beg + i] = stage[i];
}

// ---- LDS-tiled register-blocked GEMM, fp32 accumulate, fp16 output ----
// Epilogue pre-scales each output row by dinv[row]: h'[n] = (a@w)[n]*dinv[n].
template <int K, typename TIn>
__global__ __launch_bounds__(256) void k_mm(const TIn* __restrict__ a,
                                            const float* __restrict__ w,
                                            const float* __restrict__ dinv,
                                            __half* __restrict__ out) {
    __shared__ __align__(16) float At[K * 68];
    __shared__ __align__(16) float Ws[K * HIDDEN];
    int tid = threadIdx.x;
    long nbase = (long)blockIdx.x * 64;

    for (int i = tid; i < K * 16; i += 256)
        *(float4*)&Ws[i * 4] = *(const float4*)&w[i * 4];
    for (int i = tid; i < K * 16; i += 256) {
        int node = (i * 4) / K;
        int k = (i * 4) % K;
        long gn = nbase + node;
        float4 v;
        if (gn < N_NODES) {
            if constexpr (sizeof(TIn) == 2) {
                __half2 p0 = *(const __half2*)&a[gn * K + k];
                __half2 p1 = *(const __half2*)&a[gn * K + k + 2];
                float2 f0 = __half22float2(p0), f1 = __half22float2(p1);
                v = make_float4(f0.x, f0.y, f1.x, f1.y);
            } else {
                v = *(const float4*)&a[gn * K + k];
            }
        } else v = make_float4(0.f, 0.f, 0.f, 0.f);
        At[(k + 0) * 68 + node] = v.x;
        At[(k + 1) * 68 + node] = v.y;
        At[(k + 2) * 68 + node] = v.z;
        At[(k + 3) * 68 + node] = v.w;
    }
    __syncthreads();

    int tx = tid & 15;
    int ty = tid >> 4;
    float acc[4][4] = {};
#pragma unroll 8
    for (int k = 0; k < K; ++k) {
        float av[4], wv[4];
        *(float4*)av = *(const float4*)&At[k * 68 + ty * 4];
        *(float4*)wv = *(const float4*)&Ws[k * HIDDEN + tx * 4];
#pragma unroll
        for (int i = 0; i < 4; ++i)
#pragma unroll
            for (int j = 0; j < 4; ++j)
                acc[i][j] = fmaf(av[i], wv[j], acc[i][j]);
    }
#pragma unroll
    for (int i = 0; i < 4; ++i) {
        long n = nbase + ty * 4 + i;
        if (n < N_NODES) {
            float di = dinv[n];
            __half2* op = (__half2*)&out[n * HIDDEN + tx * 4];
            op[0] = __floats2half2_rn(acc[i][0] * di, acc[i][1] * di);
            op[1] = __floats2half2_rn(acc[i][2] * di, acc[i][3] * di);
        }
    }
}

// add one fp16 row-octet (int4 = 8 halves) into fp32 accumulators
__device__ __forceinline__ void acc_row8(float* a, int4 rv) {
    float2 f;
    f = __half22float2(*(__half2*)&rv.x); a[0] += f.x; a[1] += f.y;
    f = __half22float2(*(__half2*)&rv.y); a[2] += f.x; a[3] += f.y;
    f = __half22float2(*(__half2*)&rv.z); a[4] += f.x; a[5] += f.y;
    f = __half22float2(*(__half2*)&rv.w); a[6] += f.x; a[7] += f.y;
}

// octet-scheme gather body: leaves ALL lanes holding the full octet sums a[0..7]
// for feature octet q = lane&7 (edge slots reduced via 3-stage butterfly).
__device__ __forceinline__ void gather_body(const __half* __restrict__ h,
                                            const int* __restrict__ csr,
                                            int node, int e8, int q, int r0, int r1,
                                            float* a) {
    if (e8 == 0)  // self-loop row counted once
        acc_row8(a, *(const int4*)&h[(long)node * HIDDEN + q * 8]);
    int j = r0;
    while (j + 16 <= r1) {  // 16 edges: 2 independent 8-row batches in flight
        int sA = csr[j + e8];
        int sB = csr[j + 8 + e8];
        int4 rA = *(const int4*)&h[(long)sA * HIDDEN + q * 8];
        int4 rB = *(const int4*)&h[(long)sB * HIDDEN + q * 8];
        acc_row8(a, rA);
        acc_row8(a, rB);
        j += 16;
    }
    if (j + 8 <= r1) {
        int sA = csr[j + e8];
        acc_row8(a, *(const int4*)&h[(long)sA * HIDDEN + q * 8]);
        j += 8;
    }
    int rem = r1 - j;  // 0..7
    if (e8 < rem) {
        int sA = csr[j + e8];
        acc_row8(a, *(const int4*)&h[(long)sA * HIDDEN + q * 8]);
    }
#pragma unroll
    for (int off = 8; off < 64; off <<= 1)
#pragma unroll
        for (int i = 0; i < 8; ++i) a[i] += __shfl_xor(a[i], off, 64);
}

// ---- layer-1 aggregation: out[d,:] = relu(dinv[d]*(sum h'[src] + h'[d]) + b) ----
__global__ void k_gather(const __half* __restrict__ h, const int* __restrict__ csr,
                         const int2* __restrict__ rse, const float* __restrict__ dinv,
                         const float* __restrict__ bias, __half* __restrict__ out) {
    int t = blockIdx.x * 256 + threadIdx.x;
    int node = __builtin_amdgcn_readfirstlane(t >> 6);  // wave-uniform
    int lane = t & 63;
    int e8 = lane >> 3;
    int q = lane & 7;
    int2 se = rse[node];
    float dd = dinv[node];
    float a[8] = {0.f, 0.f, 0.f, 0.f, 0.f, 0.f, 0.f, 0.f};
    gather_body(h, csr, node, e8, q, se.x, se.x + se.y, a);

    if (e8 == 0) {
        float4 b0 = *(const float4*)&bias[q * 8];
        float4 b1 = *(const float4*)&bias[q * 8 + 4];
        float r[8];
        r[0] = fmaxf(fmaf(a[0], dd, b0.x), 0.f);
        r[1] = fmaxf(fmaf(a[1], dd, b0.y), 0.f);
        r[2] = fmaxf(fmaf(a[2], dd, b0.z), 0.f);
        r[3] = fmaxf(fmaf(a[3], dd, b0.w), 0.f);
        r[4] = fmaxf(fmaf(a[4], dd, b1.x), 0.f);
        r[5] = fmaxf(fmaf(a[5], dd, b1.y), 0.f);
        r[6] = fmaxf(fmaf(a[6], dd, b1.z), 0.f);
        r[7] = fmaxf(fmaf(a[7], dd, b1.w), 0.f);
        __half2 h0 = __floats2half2_rn(r[0], r[1]);
        __half2 h1 = __floats2half2_rn(r[2], r[3]);
        __half2 h2 = __floats2half2_rn(r[4], r[5]);
        __half2 h3 = __floats2half2_rn(r[6], r[7]);
        int4 o;
        o.x = *(int*)&h0; o.y = *(int*)&h1; o.z = *(int*)&h2; o.w = *(int*)&h3;
        *(int4*)&out[(long)node * HIDDEN + q * 8] = o;
    }
}

// ---- layer-2 aggregation FUSED with output matmul + softmax ----
// After gather_body, all lanes hold octet sums. Lane (q,e8) computes class
// partials c0=2*e8, c1=2*e8+1 over its 8 features (WT[c][k] staged in LDS:
// 2-way banks = free, same-address broadcast across c). Reduce over q = 6
// shuffles; softmax max/sum over e8 = 6 shuffles; lanes q==0 store float2.
__global__ void k_gather_out(const __half* __restrict__ h, const int* __restrict__ csr,
                             const int2* __restrict__ rse, const float* __restrict__ dinv,
                             const float* __restrict__ bias,
                             const float* __restrict__ wout, const float* __restrict__ bout,
                             float* __restrict__ out) {
    __shared__ float WT[N_CLASSES * 64];  // WT[c*64+k] = wout[k*16+c]
    __shared__ float bs[N_CLASSES];
    int tid = threadIdx.x;
    for (int i = tid; i < N_CLASSES * 64; i += 256) {
        int c = i >> 6, k = i & 63;
        WT[i] = wout[k * N_CLASSES + c];
    }
    if (tid < N_CLASSES) bs[tid] = bout[tid];
    __syncthreads();

    int t = blockIdx.x * 256 + tid;
    int node = __builtin_amdgcn_readfirstlane(t >> 6);
    int lane = t & 63;
    int e8 = lane >> 3;
    int q = lane & 7;
    int2 se = rse[node];
    float dd = dinv[node];
    float a[8] = {0.f, 0.f, 0.f, 0.f, 0.f, 0.f, 0.f, 0.f};
    gather_body(h, csr, node, e8, q, se.x, se.x + se.y, a);

    // relu'd features of octet q (identical across the 8 e8 copies)
    float4 b0 = *(const float4*)&bias[q * 8];
    float4 b1 = *(const float4*)&bias[q * 8 + 4];
    float f[8];
    f[0] = fmaxf(fmaf(a[0], dd, b0.x), 0.f);
    f[1] = fmaxf(fmaf(a[1], dd, b0.y), 0.f);
    f[2] = fmaxf(fmaf(a[2], dd, b0.z), 0.f);
    f[3] = fmaxf(fmaf(a[3], dd, b0.w), 0.f);
    f[4] = fmaxf(fmaf(a[4], dd, b1.x), 0.f);
    f[5] = fmaxf(fmaf(a[5], dd, b1.y), 0.f);
    f[6] = fmaxf(fmaf(a[6], dd, b1.z), 0.f);
    f[7] = fmaxf(fmaf(a[7], dd, b1.w), 0.f);

    int c0 = e8 * 2;
    float p0 = 0.f, p1 = 0.f;
#pragma unroll
    for (int i = 0; i < 8; ++i) {
        p0 = fmaf(f[i], WT[c0 * 64 + q * 8 + i], p0);
        p1 = fmaf(f[i], WT[(c0 + 1) * 64 + q * 8 + i], p1);
    }
    // reduce partials over q (bits 0..2)
    p0 += __shfl_xor(p0, 1); p0 += __shfl_xor(p0, 2); p0 += __shfl_xor(p0, 4);
    p1 += __shfl_xor(p1, 1); p1 += __shfl_xor(p1, 2); p1 += __shfl_xor(p1, 4);
    p0 += bs[c0];
    p1 += bs[c0 + 1];
    // softmax over the 16 classes spread across e8 (bits 3..5), 2 per lane
    float m = fmaxf(p0, p1);
    m = fmaxf(m, __shfl_xor(m, 8));
    m = fmaxf(m, __shfl_xor(m, 16));
    m = fmaxf(m, __shfl_xor(m, 32));
    float e0 = __expf(p0 - m), e1 = __expf(p1 - m);
    float s = e0 + e1;
    s += __shfl_xor(s, 8);
    s += __shfl_xor(s, 16);
    s += __shfl_xor(s, 32);
    if (q == 0) {
        float inv = 1.0f / s;
        *(float2*)&out[(long)node * N_CLASSES + c0] = make_float2(e0 * inv, e1 * inv);
    }
}

extern "C" void kernel_launch(void* const* d_in, const int* in_sizes, int n_in,
                              void* d_out, int out_size, void* d_ws, size_t ws_size,
                              hipStream_t stream) {
    const float* x    = (const float*)d_in[0];
    const int*   ei   = (const int*)d_in[1];
    const float* W1   = (const float*)d_in[2];
    const float* b1   = (const float*)d_in[3];
    const float* W2   = (const float*)d_in[4];
    const float* b2   = (const float*)d_in[5];
    const float* Wout = (const float*)d_in[6];
    const float* bout = (const float*)d_in[7];
    float* out = (float*)d_out;

    char* ws = (char*)d_ws;
    int2*   rse     = (int2*)ws;                       ws += 400128;   // 50000 int2
    float*  dinv    = (float*)ws;                      ws += 200192;   // 50000 f32
    int*    tileCur = (int*)ws;                        ws += 1024;
    int*    csr     = (int*)ws;                        ws += (size_t)NBLK_NODE * TCAP * 4;  // 6.42 MB
    char*   slotA   = ws;                              ws += 6553600;  // max(binned, bufA)
    __half* bufB    = (__half*)ws;
    int*    binned  = (int*)slotA;        // dies before k_mm<128> writes bufA
    __half* bufA    = (__half*)slotA;

    const int NB_MM = (N_NODES + 63) / 64;        // 782
    const int NB_E16 = (N_EDGES + 4095) / 4096;   // 196

    // ---- CSR build: bucketed partition -> counting sort (+deg/dinv/rse) ----
    k_init<<<1, 256, 0, stream>>>(tileCur);
    k_part<<<NB_E16, 256, 0, stream>>>(ei, tileCur, binned);
    k_finesort<<<NBLK_NODE, 256, 0, stream>>>(binned, tileCur, csr, rse, dinv);

    // ---- layer 1 (mm output pre-scaled by dinv; gather is a pure row-sum) ----
    k_mm<N_FEAT, float><<<NB_MM, 256, 0, stream>>>(x, W1, dinv, bufA);
    k_gather<<<N_NODES / 4, 256, 0, stream>>>(bufA, csr, rse, dinv, b1, bufB);

    // ---- layer 2 + output matmul + softmax (fused epilogue) ----
    k_mm<HIDDEN, __half><<<NB_MM, 256, 0, stream>>>(bufB, W2, dinv, bufA);
    k_gather_out<<<N_NODES / 4, 256, 0, stream>>>(bufA, csr, rse, dinv, b2, Wout, bout, out);
}

// Round 12
// 171.528 us; speedup vs baseline: 1.1930x; 1.1930x over previous
//
#include <hip/hip_runtime.h>
#include <hip/hip_fp16.h>

#define N_NODES 50000
#define N_EDGES 800000
#define N_FEAT 128
#define HIDDEN 64
#define N_CLASSES 16
#define NBLK_NODE 196   // number of 256-node dst tiles (ceil(50000/256))
#define TCAP 8192       // per-tile bucket capacity (recs); mean 4083, sigma ~64

typedef _Float16 f16x8 __attribute__((ext_vector_type(8)));
typedef float f32x4 __attribute__((ext_vector_type(4)));

// tileCur[t] = t*TCAP (bucket base cursors)
__global__ void k_init(int* __restrict__ tileCur) {
    int tid = threadIdx.x;
    if (tid < NBLK_NODE) tileCur[tid] = tid * TCAP;
}

// Partition edges into 196 fixed-capacity dst-tile buckets. Per block: LDS
// histogram, ONE global atomic per (block,tile) reserves a contiguous sub-run
// -> block-owned 4B record stores merge in L2. record: src | dstLocal<<16
__global__ __launch_bounds__(256) void k_part(const int* __restrict__ ei,
                                              int* __restrict__ tileCur,
                                              int* __restrict__ binned) {
    __shared__ int cnt[NBLK_NODE], base[NBLK_NODE], cur[NBLK_NODE];
    int tid = threadIdx.x;
    int start = blockIdx.x * 4096;
    if (tid < NBLK_NODE) cnt[tid] = 0;
    __syncthreads();
    int s[16], d[16];
#pragma unroll
    for (int u = 0; u < 4; ++u) {
        int e0 = start + u * 1024 + tid * 4;
        if (e0 + 4 <= N_EDGES) {
            int4 s4 = *(const int4*)&ei[e0];
            int4 d4 = *(const int4*)&ei[N_EDGES + e0];
            s[u * 4 + 0] = s4.x; s[u * 4 + 1] = s4.y; s[u * 4 + 2] = s4.z; s[u * 4 + 3] = s4.w;
            d[u * 4 + 0] = d4.x; d[u * 4 + 1] = d4.y; d[u * 4 + 2] = d4.z; d[u * 4 + 3] = d4.w;
#pragma unroll
            for (int q = 0; q < 4; ++q) atomicAdd(&cnt[d[u * 4 + q] >> 8], 1);
        } else {
#pragma unroll
            for (int q = 0; q < 4; ++q) {
                int e = e0 + q;
                if (e < N_EDGES) {
                    s[u * 4 + q] = ei[e];
                    d[u * 4 + q] = ei[N_EDGES + e];
                    atomicAdd(&cnt[d[u * 4 + q] >> 8], 1);
                } else s[u * 4 + q] = -1;
            }
        }
    }
    __syncthreads();
    if (tid < NBLK_NODE) {
        base[tid] = atomicAdd(&tileCur[tid], cnt[tid]);
        cur[tid] = 0;
    }
    __syncthreads();
#pragma unroll
    for (int u = 0; u < 16; ++u) {
        if (s[u] < 0) continue;
        int t = d[u] >> 8;
        int r = atomicAdd(&cur[t], 1);
        int p = base[t] + r;
        if (p < (t + 1) * TCAP)  // bucket-bound guard (never hit for uniform input)
            binned[p] = s[u] | ((d[u] & 255) << 16);
    }
}

// Per-tile counting sort (bucketed layout). Also derives degree -> dinv and
// per-node {start,count} rse. Fully LDS-staged; coalesced int4 csr writes.
__global__ __launch_bounds__(256) void k_finesort(const int* __restrict__ binned,
                                                  const int* __restrict__ tileCur,
                                                  int* __restrict__ csr,
                                                  int2* __restrict__ rse,
                                                  float* __restrict__ dinv) {
    __shared__ int stage[TCAP];
    __shared__ int sc[256];
    __shared__ int cnt256[256];
    __shared__ int nodeOff[256];
    int tid = threadIdx.x;
    int tb = blockIdx.x;
    int beg = tb * TCAP;
    int m = tileCur[tb] - beg;
    if (m > TCAP) m = TCAP;
    cnt256[tid] = 0;
    __syncthreads();
    const int4* b4 = (const int4*)(binned + beg);
    int nv = m >> 2;
    for (int i = tid; i < nv; i += 256) {
        int4 r = b4[i];
        atomicAdd(&cnt256[(r.x >> 16) & 255], 1);
        atomicAdd(&cnt256[(r.y >> 16) & 255], 1);
        atomicAdd(&cnt256[(r.z >> 16) & 255], 1);
        atomicAdd(&cnt256[(r.w >> 16) & 255], 1);
    }
    for (int i = (m & ~3) + tid; i < m; i += 256)
        atomicAdd(&cnt256[(binned[beg + i] >> 16) & 255], 1);
    __syncthreads();
    int myc = cnt256[tid];
    sc[tid] = myc;
    __syncthreads();
#pragma unroll
    for (int off = 1; off < 256; off <<= 1) {
        int t = (tid >= off) ? sc[tid - off] : 0;
        __syncthreads();
        sc[tid] += t;
        __syncthreads();
    }
    int off0 = sc[tid] - myc;
    nodeOff[tid] = off0;
    int gnode = tb * 256 + tid;
    if (gnode < N_NODES) {
        dinv[gnode] = rsqrtf((float)myc + 1.0f);  // deg = in-edges + self-loop
        rse[gnode] = make_int2(beg + off0, myc);
    }
    cnt256[tid] = 0;
    __syncthreads();
    for (int i = tid; i < nv; i += 256) {
        int4 r = b4[i];
        int rr;
        rr = atomicAdd(&cnt256[(r.x >> 16) & 255], 1); stage[nodeOff[(r.x >> 16) & 255] + rr] = r.x & 0xFFFF;
        rr = atomicAdd(&cnt256[(r.y >> 16) & 255], 1); stage[nodeOff[(r.y >> 16) & 255] + rr] = r.y & 0xFFFF;
        rr = atomicAdd(&cnt256[(r.z >> 16) & 255], 1); stage[nodeOff[(r.z >> 16) & 255] + rr] = r.z & 0xFFFF;
        rr = atomicAdd(&cnt256[(r.w >> 16) & 255], 1); stage[nodeOff[(r.w >> 16) & 255] + rr] = r.w & 0xFFFF;
    }
    for (int i = (m & ~3) + tid; i < m; i += 256) {
        int rec = binned[beg + i];
        int dl = (rec >> 16) & 255;
        int rr = atomicAdd(&cnt256[dl], 1);
        stage[nodeOff[dl] + rr] = rec & 0xFFFF;
    }
    __syncthreads();
    int4* c4 = (int4*)(csr + beg);
    for (int i = tid; i < nv; i += 256) c4[i] = ((const int4*)stage)[i];
    for (int i = (m & ~3) + tid; i < m; i += 256) csr[beg + i] = stage[i];
}

// ---- MFMA GEMM: out[n,f] = (A @ W)[n,f] * dinv[n], fp16 out ----
// Block = 256 thr = 4 waves = 64 nodes; wave w covers nodes nbase+16w..+15.
// mfma_f32_16x16x32_f16; A-frag A[m=lane&15][k=quad*8+j]; B-frag
// B[k=quad*8+j][n=lane&15]; D row=quad*4+reg, col=lane&15 (verified layouts).
// A and W staged k-contiguous in LDS, stride K+8 halves (2-way banks = free).
template <int K, typename TIn>
__global__ __launch_bounds__(256) void k_mm(const TIn* __restrict__ a,
                                            const float* __restrict__ w,
                                            const float* __restrict__ dinv,
                                            __half* __restrict__ out) {
    constexpr int LDK = K + 8;
    __shared__ __align__(16) __half A_lds[64 * LDK];
    __shared__ __align__(16) __half Wt_lds[64 * LDK];
    int tid = threadIdx.x;
    long nbase = (long)blockIdx.x * 64;

    // stage W transposed: w[k*64+f] (fp32) -> Wt_lds[f][k] (fp16)
    for (int i = tid; i < K * 16; i += 256) {
        int k = (i * 4) >> 6;
        int f0 = (i * 4) & 63;
        float4 v = *(const float4*)&w[i * 4];
        Wt_lds[(f0 + 0) * LDK + k] = __float2half(v.x);
        Wt_lds[(f0 + 1) * LDK + k] = __float2half(v.y);
        Wt_lds[(f0 + 2) * LDK + k] = __float2half(v.z);
        Wt_lds[(f0 + 3) * LDK + k] = __float2half(v.w);
    }
    // stage A rows -> A_lds[n][k] fp16 (8-elem chunks)
    for (int i = tid; i < 64 * K / 8; i += 256) {
        int n = (i * 8) / K;
        int k0 = (i * 8) % K;
        long gn = nbase + n;
        if constexpr (sizeof(TIn) == 4) {
            float4 v0, v1;
            if (gn < N_NODES) {
                v0 = *(const float4*)&a[gn * K + k0];
                v1 = *(const float4*)&a[gn * K + k0 + 4];
            } else {
                v0 = make_float4(0.f, 0.f, 0.f, 0.f);
                v1 = v0;
            }
            __half2* dst = (__half2*)&A_lds[n * LDK + k0];
            dst[0] = __floats2half2_rn(v0.x, v0.y);
            dst[1] = __floats2half2_rn(v0.z, v0.w);
            dst[2] = __floats2half2_rn(v1.x, v1.y);
            dst[3] = __floats2half2_rn(v1.z, v1.w);
        } else {
            int4 v = (gn < N_NODES) ? *(const int4*)&a[gn * K + k0]
                                    : make_int4(0, 0, 0, 0);
            *(int4*)&A_lds[n * LDK + k0] = v;
        }
    }
    __syncthreads();

    int wv = tid >> 6;
    int lane = tid & 63;
    int m = lane & 15;      // A row within wave tile / D col
    int quad = lane >> 4;   // 0..3
    const __half* Arow = &A_lds[(wv * 16 + m) * LDK + quad * 8];
    f32x4 acc[4] = {};      // 4 feature col-tiles of 16
#pragma unroll
    for (int t = 0; t < K; t += 32) {
        f16x8 af = *(const f16x8*)(const void*)&Arow[t];
#pragma unroll
        for (int g = 0; g < 4; ++g) {
            f16x8 bf = *(const f16x8*)(const void*)&Wt_lds[(g * 16 + m) * LDK + t + quad * 8];
            acc[g] = __builtin_amdgcn_mfma_f32_16x16x32_f16(af, bf, acc[g], 0, 0, 0);
        }
    }

    // D: row(node) = quad*4 + r, col(feat) = g*16 + m
#pragma unroll
    for (int r = 0; r < 4; ++r) {
        int n = wv * 16 + quad * 4 + r;
        long gn = nbase + n;
        if (gn < N_NODES) {
            float di = dinv[gn];
#pragma unroll
            for (int g = 0; g < 4; ++g)
                out[gn * HIDDEN + g * 16 + m] = __float2half(acc[g][r] * di);
        }
    }
}

// add one fp16 row-octet (int4 = 8 halves) into fp32 accumulators
__device__ __forceinline__ void acc_row8(float* a, int4 rv) {
    float2 f;
    f = __half22float2(*(__half2*)&rv.x); a[0] += f.x; a[1] += f.y;
    f = __half22float2(*(__half2*)&rv.y); a[2] += f.x; a[3] += f.y;
    f = __half22float2(*(__half2*)&rv.z); a[4] += f.x; a[5] += f.y;
    f = __half22float2(*(__half2*)&rv.w); a[6] += f.x; a[7] += f.y;
}

// ---- fused aggregation on pre-scaled rows: pure row-sum, OCTET scheme ----
// out[d,:] = relu( dinv[d] * (sum_e h'[src] + h'[d]) + b )
// One wave per node. lane = {edge slot e8 = lane>>3, feature octet q = lane&7}.
__global__ void k_gather(const __half* __restrict__ h, const int* __restrict__ csr,
                         const int2* __restrict__ rse, const float* __restrict__ dinv,
                         const float* __restrict__ bias, __half* __restrict__ out) {
    int t = blockIdx.x * 256 + threadIdx.x;
    int node = __builtin_amdgcn_readfirstlane(t >> 6);  // wave-uniform
    int lane = t & 63;
    int e8 = lane >> 3;   // edge slot 0..7
    int q = lane & 7;     // features q*8 .. q*8+7
    int2 se = rse[node];
    int r0 = se.x, r1 = se.x + se.y;
    float dd = dinv[node];

    float a[8] = {0.f, 0.f, 0.f, 0.f, 0.f, 0.f, 0.f, 0.f};
    if (e8 == 0)  // self-loop row counted once
        acc_row8(a, *(const int4*)&h[(long)node * HIDDEN + q * 8]);

    int j = r0;
    while (j + 16 <= r1) {  // 16 edges: 2 independent 8-row batches in flight
        int sA = csr[j + e8];
        int sB = csr[j + 8 + e8];
        int4 rA = *(const int4*)&h[(long)sA * HIDDEN + q * 8];
        int4 rB = *(const int4*)&h[(long)sB * HIDDEN + q * 8];
        acc_row8(a, rA);
        acc_row8(a, rB);
        j += 16;
    }
    if (j + 8 <= r1) {
        int sA = csr[j + e8];
        acc_row8(a, *(const int4*)&h[(long)sA * HIDDEN + q * 8]);
        j += 8;
    }
    int rem = r1 - j;  // 0..7
    if (e8 < rem) {
        int sA = csr[j + e8];
        acc_row8(a, *(const int4*)&h[(long)sA * HIDDEN + q * 8]);
    }
    // reduce across the 8 edge slots
#pragma unroll
    for (int off = 8; off < 64; off <<= 1)
#pragma unroll
        for (int i = 0; i < 8; ++i) a[i] += __shfl_xor(a[i], off, 64);

    if (e8 == 0) {
        float4 b0 = *(const float4*)&bias[q * 8];
        float4 b1 = *(const float4*)&bias[q * 8 + 4];
        float r[8];
        r[0] = fmaxf(fmaf(a[0], dd, b0.x), 0.f);
        r[1] = fmaxf(fmaf(a[1], dd, b0.y), 0.f);
        r[2] = fmaxf(fmaf(a[2], dd, b0.z), 0.f);
        r[3] = fmaxf(fmaf(a[3], dd, b0.w), 0.f);
        r[4] = fmaxf(fmaf(a[4], dd, b1.x), 0.f);
        r[5] = fmaxf(fmaf(a[5], dd, b1.y), 0.f);
        r[6] = fmaxf(fmaf(a[6], dd, b1.z), 0.f);
        r[7] = fmaxf(fmaf(a[7], dd, b1.w), 0.f);
        __half2 h0 = __floats2half2_rn(r[0], r[1]);
        __half2 h1 = __floats2half2_rn(r[2], r[3]);
        __half2 h2 = __floats2half2_rn(r[4], r[5]);
        __half2 h3 = __floats2half2_rn(r[6], r[7]);
        int4 o;
        o.x = *(int*)&h0; o.y = *(int*)&h1; o.z = *(int*)&h2; o.w = *(int*)&h3;
        *(int4*)&out[(long)node * HIDDEN + q * 8] = o;
    }
}

// ---- logits = h @ Wout + bout, softmax over 16 classes (fp32 math) ----
__global__ void k_out(const __half* __restrict__ h, const float* __restrict__ w,
                      const float* __restrict__ b, float* __restrict__ out) {
    __shared__ float Ws[HIDDEN * N_CLASSES];
    __shared__ float bs[N_CLASSES];
    int tid = threadIdx.x;
    for (int i = tid; i < HIDDEN * N_CLASSES; i += 256) Ws[i] = w[i];
    if (tid < N_CLASSES) bs[tid] = b[tid];
    __syncthreads();
    int node = blockIdx.x * 16 + (tid >> 4);
    int c = tid & 15;
    const __half* hr = h + (long)node * HIDDEN;
    float acc = bs[c];
#pragma unroll
    for (int k = 0; k < HIDDEN; ++k)
        acc = fmaf(__half2float(hr[k]), Ws[k * N_CLASSES + c], acc);
    float m = acc;
#pragma unroll
    for (int off = 8; off; off >>= 1) m = fmaxf(m, __shfl_xor(m, off, 16));
    float ex = expf(acc - m);
    float s = ex;
#pragma unroll
    for (int off = 8; off; off >>= 1) s += __shfl_xor(s, off, 16);
    out[(long)node * N_CLASSES + c] = ex / s;
}

extern "C" void kernel_launch(void* const* d_in, const int* in_sizes, int n_in,
                              void* d_out, int out_size, void* d_ws, size_t ws_size,
                              hipStream_t stream) {
    const float* x    = (const float*)d_in[0];
    const int*   ei   = (const int*)d_in[1];
    const float* W1   = (const float*)d_in[2];
    const float* b1   = (const float*)d_in[3];
    const float* W2   = (const float*)d_in[4];
    const float* b2   = (const float*)d_in[5];
    const float* Wout = (const float*)d_in[6];
    const float* bout = (const float*)d_in[7];
    float* out = (float*)d_out;

    char* ws = (char*)d_ws;
    int2*   rse     = (int2*)ws;                       ws += 400128;   // 50000 int2
    float*  dinv    = (float*)ws;                      ws += 200192;   // 50000 f32
    int*    tileCur = (int*)ws;                        ws += 1024;
    int*    csr     = (int*)ws;                        ws += (size_t)NBLK_NODE * TCAP * 4;  // 6.42 MB
    char*   slotA   = ws;                              ws += 6553600;  // max(binned, bufA)
    __half* bufB    = (__half*)ws;
    int*    binned  = (int*)slotA;        // dies before k_mm<128> writes bufA
    __half* bufA    = (__half*)slotA;

    const int NB_MM = (N_NODES + 63) / 64;        // 782
    const int NB_E16 = (N_EDGES + 4095) / 4096;   // 196

    // ---- CSR build: bucketed partition -> counting sort (+deg/dinv/rse) ----
    k_init<<<1, 256, 0, stream>>>(tileCur);
    k_part<<<NB_E16, 256, 0, stream>>>(ei, tileCur, binned);
    k_finesort<<<NBLK_NODE, 256, 0, stream>>>(binned, tileCur, csr, rse, dinv);

    // ---- layer 1 (mm output pre-scaled by dinv; gather is a pure row-sum) ----
    k_mm<N_FEAT, float><<<NB_MM, 256, 0, stream>>>(x, W1, dinv, bufA);
    k_gather<<<N_NODES / 4, 256, 0, stream>>>(bufA, csr, rse, dinv, b1, bufB);

    // ---- layer 2 ----
    k_mm<HIDDEN, __half><<<NB_MM, 256, 0, stream>>>(bufB, W2, dinv, bufA);
    k_gather<<<N_NODES / 4, 256, 0, stream>>>(bufA, csr, rse, dinv, b2, bufB);

    // ---- output layer + softmax ----
    k_out<<<N_NODES / 16, 256, 0, stream>>>(bufB, Wout, bout, out);
}